// Round 2
// baseline (11389.129 us; speedup 1.0000x reference)
//
#include <hip/hip_runtime.h>

#define EPSF 1e-6f
#define ONEM 0.999999f
#define Bb 256
#define Tt 128
#define Kd 1024

typedef __attribute__((ext_vector_type(8))) short s16x8;
typedef __attribute__((ext_vector_type(4))) short s16x4;
typedef __attribute__((ext_vector_type(4))) float f32x4;

__device__ __forceinline__ short f2bf(float f) {
  unsigned u = __float_as_uint(f);
  u += 0x7fffu + ((u >> 16) & 1u);
  return (short)(u >> 16);
}
__device__ __forceinline__ float bf2f(short s) {
  return __uint_as_float(((unsigned)(unsigned short)s) << 16);
}

// block-wide sum over 256 threads (4 waves)
__device__ __forceinline__ float brsum(float v) {
  __shared__ float sb[4];
#pragma unroll
  for (int m = 32; m >= 1; m >>= 1) v += __shfl_xor(v, m, 64);
  __syncthreads();  // protect sb from previous use
  if ((threadIdx.x & 63) == 0) sb[threadIdx.x >> 6] = v;
  __syncthreads();
  return sb[0] + sb[1] + sb[2] + sb[3];
}

// manual all-resident grid barrier: 64 padded counters, wave-0 parallel poll
__device__ __forceinline__ void gbar(int* cnt, int bid, int tid, int target) {
  __syncthreads();
  __threadfence();  // release
  if (tid == 0)
    __hip_atomic_fetch_add(&cnt[(bid & 63) << 5], 1, __ATOMIC_RELAXED,
                           __HIP_MEMORY_SCOPE_AGENT);
  if (tid < 64) {
    for (;;) {
      int v = __hip_atomic_load(&cnt[tid << 5], __ATOMIC_RELAXED,
                                __HIP_MEMORY_SCOPE_AGENT);
      if (__all(v >= target)) break;
      __builtin_amdgcn_s_sleep(2);
    }
  }
  __syncthreads();
  __threadfence();  // acquire
}

// ---- phase 0a: transpose+convert W (1024x1024 f32 [k][n]) -> WT bf16 [n][k]
// 64x64 tile per block = 4096 elems, 256 threads -> 16 elems/thread.
__global__ void wcvt_kernel(const float* __restrict__ Wih,
                            const float* __restrict__ Whh,
                            short* __restrict__ WTih, short* __restrict__ WThh) {
  __shared__ float tile[64][65];
  const float* src = blockIdx.z ? Whh : Wih;
  short* dst = blockIdx.z ? WThh : WTih;
  const int k0 = blockIdx.y * 64, n0 = blockIdx.x * 64;
  const int t = threadIdx.x;
#pragma unroll
  for (int i = 0; i < 16; i++) {
    int e = i * 256 + t, r = e >> 6, c = e & 63;
    tile[r][c] = src[(k0 + r) * Kd + n0 + c];
  }
  __syncthreads();
#pragma unroll
  for (int i = 0; i < 16; i++) {
    int e = i * 256 + t, rn = e >> 6, ck = e & 63;
    dst[(n0 + rn) * Kd + k0 + ck] = f2bf(tile[ck][rn]);
  }
}

// ---- phase 0b: convert inp f32 -> bf16 (8 elems/thread)
__global__ void icvt_kernel(const float* __restrict__ inp, short* __restrict__ out) {
  int i = blockIdx.x * 2048 + threadIdx.x * 8;
  float4 a = *(const float4*)(inp + i);
  float4 b = *(const float4*)(inp + i + 4);
  s16x8 v;
  v[0] = f2bf(a.x); v[1] = f2bf(a.y); v[2] = f2bf(a.z); v[3] = f2bf(a.w);
  v[4] = f2bf(b.x); v[5] = f2bf(b.y); v[6] = f2bf(b.z); v[7] = f2bf(b.w);
  *(s16x8*)(out + i) = v;
}

// ---- phase 1: P_raw = inp_bf16 @ W_ih  (A[M][K] row-major, BT[N][K] row-major)
// 64x64 tile per block; 4 waves, wave w = rows w*16..+16; 4 MFMA accs along N.
__global__ void __launch_bounds__(256) gemm_p_kernel(const short* __restrict__ A,
                                                     const short* __restrict__ BT,
                                                     short* __restrict__ C) {
  const int n0 = blockIdx.x * 64, m0 = blockIdx.y * 64;
  const int tid = threadIdx.x, w = tid >> 6, l = tid & 63, lm = l & 15, q = l >> 4;
  const short* ap = A + (m0 + w * 16 + lm) * Kd + q * 8;
  const short* bp = BT + (n0 + lm) * Kd + q * 8;
  f32x4 acc0 = {0.f, 0.f, 0.f, 0.f}, acc1 = acc0, acc2 = acc0, acc3 = acc0;
#pragma unroll 4
  for (int k = 0; k < Kd; k += 32) {
    s16x8 a = *(const s16x8*)(ap + k);
    s16x8 b0 = *(const s16x8*)(bp + k);
    s16x8 b1 = *(const s16x8*)(bp + 16 * Kd + k);
    s16x8 b2 = *(const s16x8*)(bp + 32 * Kd + k);
    s16x8 b3 = *(const s16x8*)(bp + 48 * Kd + k);
    acc0 = __builtin_amdgcn_mfma_f32_16x16x32_bf16(a, b0, acc0, 0, 0, 0);
    acc1 = __builtin_amdgcn_mfma_f32_16x16x32_bf16(a, b1, acc1, 0, 0, 0);
    acc2 = __builtin_amdgcn_mfma_f32_16x16x32_bf16(a, b2, acc2, 0, 0, 0);
    acc3 = __builtin_amdgcn_mfma_f32_16x16x32_bf16(a, b3, acc3, 0, 0, 0);
  }
  const int row = m0 + w * 16 + q * 4, col = n0 + lm;
#pragma unroll
  for (int r = 0; r < 4; r++) {
    C[(row + r) * Kd + col] = f2bf(acc0[r]);
    C[(row + r) * Kd + col + 16] = f2bf(acc1[r]);
    C[(row + r) * Kd + col + 32] = f2bf(acc2[r]);
    C[(row + r) * Kd + col + 48] = f2bf(acc3[r]);
  }
}

// ---- phase 1b: per-row mobius_matvec scaling of P (in place), store pn2
__global__ void __launch_bounds__(256) rowscale_kernel(const float* __restrict__ inp,
                                                       short* __restrict__ P,
                                                       float* __restrict__ pn2) {
  const int r = blockIdx.x, tid = threadIdx.x, i0 = tid * 4;
  float4 xv = *(const float4*)(inp + r * Kd + i0);
  float xn2 = brsum(xv.x * xv.x + xv.y * xv.y + xv.z * xv.z + xv.w * xv.w);
  s16x4 pr = *(const s16x4*)(P + r * Kd + i0);
  float p0 = bf2f(pr[0]), p1 = bf2f(pr[1]), p2 = bf2f(pr[2]), p3 = bf2f(pr[3]);
  float mxn2 = brsum(p0 * p0 + p1 * p1 + p2 * p2 + p3 * p3);
  float xn = fmaxf(sqrtf(xn2), EPSF);
  float mxn = fmaxf(sqrtf(mxn2), EPSF);
  float sc = tanhf(mxn / xn * atanhf(fminf(xn, ONEM))) / mxn;
  s16x4 po;
  po[0] = f2bf(sc * p0); po[1] = f2bf(sc * p1);
  po[2] = f2bf(sc * p2); po[3] = f2bf(sc * p3);
  *(s16x4*)(P + r * Kd + i0) = po;
  if (tid == 0) pn2[r] = sc * sc * mxn2;
}

// ---- phase 2: persistent recurrent kernel, 256 blocks x 256 threads
__global__ void __launch_bounds__(256) rnn_kernel(short* __restrict__ hb,
                                                  float* __restrict__ mx,
                                                  const short* __restrict__ WT,
                                                  const short* __restrict__ P,
                                                  const float* __restrict__ pn2,
                                                  const float* __restrict__ bh,
                                                  float* __restrict__ out,
                                                  int* __restrict__ cnt) {
  const int bid = blockIdx.x, tid = threadIdx.x;
  const int w = tid >> 6, l = tid & 63, lm = l & 15, q = l >> 4;
  const int m0 = (bid >> 4) * 16, n0 = (bid & 15) * 64;
  const int i0 = tid * 4;

  float4 bv = *(const float4*)(bh + i0);
  float b2 = brsum(bv.x * bv.x + bv.y * bv.y + bv.z * bv.z + bv.w * bv.w);
  float h0 = 0.f, h1 = 0.f, h2r = 0.f, h3 = 0.f;  // my h row (fp32, regs)
  float hn2c = 0.f;                               // carried ||h||^2
  int target = 0;

  const short* ap = hb + (m0 + lm) * Kd + q * 8;
  const short* bp = WT + (n0 + w * 16 + lm) * Kd + q * 8;
  float* mxw = mx + (m0 + q * 4) * Kd + n0 + w * 16 + lm;

  for (int t = 0; t < Tt; t++) {
    // GEMM: mx = h_bf16 @ W_hh  (block tile 16 x 64, wave per 16-col strip)
    f32x4 acc = {0.f, 0.f, 0.f, 0.f};
#pragma unroll 4
    for (int k = 0; k < Kd; k += 32) {
      s16x8 a = *(const s16x8*)(ap + k);
      s16x8 b = *(const s16x8*)(bp + k);
      acc = __builtin_amdgcn_mfma_f32_16x16x32_bf16(a, b, acc, 0, 0, 0);
    }
    mxw[0] = acc[0]; mxw[Kd] = acc[1]; mxw[2 * Kd] = acc[2]; mxw[3 * Kd] = acc[3];
    target += 4;
    gbar(cnt, bid, tid, target);

    // elementwise mobius chain for row bid (fp32)
    float4 mxv = *(const float4*)(mx + bid * Kd + i0);
    float mxn2 = brsum(mxv.x * mxv.x + mxv.y * mxv.y + mxv.z * mxv.z + mxv.w * mxv.w);
    float hn = fmaxf(sqrtf(hn2c), EPSF);
    float mxn = fmaxf(sqrtf(mxn2), EPSF);
    float sc = tanhf(mxn / hn * atanhf(fminf(hn, ONEM))) / mxn;
    float mv0 = sc * mxv.x, mv1 = sc * mxv.y, mv2 = sc * mxv.z, mv3 = sc * mxv.w;
    float x2 = sc * sc * mxn2;  // == sum(mv^2) exactly
    float xy = brsum(mv0 * bv.x + mv1 * bv.y + mv2 * bv.z + mv3 * bv.w);
    float den = fmaxf(1.f + 2.f * xy + x2 * b2, EPSF);
    float ca = (1.f + 2.f * xy + b2) / den, cb = (1.f - x2) / den;
    float hv0 = ca * mv0 + cb * bv.x, hv1 = ca * mv1 + cb * bv.y;
    float hv2 = ca * mv2 + cb * bv.z, hv3 = ca * mv3 + cb * bv.w;

    s16x4 pr = *(const s16x4*)(P + (bid * Tt + t) * Kd + i0);
    float p0 = bf2f(pr[0]), p1 = bf2f(pr[1]), p2v = bf2f(pr[2]), p3 = bf2f(pr[3]);
    float p2s = pn2[bid * Tt + t];
    float hh2 = brsum(hv0 * hv0 + hv1 * hv1 + hv2 * hv2 + hv3 * hv3);
    float ph = brsum(p0 * hv0 + p1 * hv1 + p2v * hv2 + p3 * hv3);
    float den2 = fmaxf(1.f + 2.f * ph + p2s * hh2, EPSF);
    float c1 = (1.f + 2.f * ph + hh2) / den2, c2 = (1.f - p2s) / den2;
    float z0 = c1 * p0 + c2 * hv0, z1 = c1 * p1 + c2 * hv1;
    float z2v = c1 * p2v + c2 * hv2, z3 = c1 * p3 + c2 * hv3;
    float z2 = brsum(z0 * z0 + z1 * z1 + z2v * z2v + z3 * z3);
    float zn = fmaxf(sqrtf(z2), EPSF);
    float g = atanhf(fminf(zn, ONEM)) / zn;
    float u0 = tanhf(g * z0), u1 = tanhf(g * z1);
    float u2v = tanhf(g * z2v), u3 = tanhf(g * z3);
    float u2 = brsum(u0 * u0 + u1 * u1 + u2v * u2v + u3 * u3);
    float un = fmaxf(sqrtf(u2), EPSF);
    float s2 = tanhf(un) / un;
    h0 = s2 * u0; h1 = s2 * u1; h2r = s2 * u2v; h3 = s2 * u3;
    hn2c = s2 * s2 * u2;  // == ||h_next||^2 exactly

    s16x4 ho;
    ho[0] = f2bf(h0); ho[1] = f2bf(h1); ho[2] = f2bf(h2r); ho[3] = f2bf(h3);
    *(s16x4*)(hb + bid * Kd + i0) = ho;
    if (t == Tt - 1) {
      float4 o; o.x = h0; o.y = h1; o.z = h2r; o.w = h3;
      *(float4*)(out + bid * Kd + i0) = o;
    }
    target += 4;
    gbar(cnt, bid, tid, target);
  }
}

extern "C" void kernel_launch(void* const* d_in, const int* in_sizes, int n_in,
                              void* d_out, int out_size, void* d_ws, size_t ws_size,
                              hipStream_t stream) {
  const float* inp = (const float*)d_in[0];  // [256][128][1024]
  const float* Wih = (const float*)d_in[1];  // [1024][1024]
  const float* Whh = (const float*)d_in[2];  // [1024][1024]
  const float* bh = (const float*)d_in[3];   // [1024]

  char* ws = (char*)d_ws;
  size_t off = 0;
  int* cnt = (int*)(ws + off); off += 8192;                    // 64 cnt x 128B
  short* hbuf = (short*)(ws + off); off += (size_t)Bb * Kd * 2; // h bf16 512KB
  float* mx = (float*)(ws + off); off += (size_t)Bb * Kd * 4;   // mx f32 1MB
  float* pn2 = (float*)(ws + off); off += (size_t)Bb * Tt * 4;  // 128KB
  short* WTih = (short*)(ws + off); off += (size_t)Kd * Kd * 2; // 2MB
  short* WThh = (short*)(ws + off); off += (size_t)Kd * Kd * 2; // 2MB
  short* Ab = (short*)(ws + off); off += (size_t)Bb * Tt * Kd * 2;  // 64MB
  short* P = (short*)(ws + off); off += (size_t)Bb * Tt * Kd * 2;   // 64MB

  // zero barrier counters + h
  hipMemsetAsync(d_ws, 0, 8192 + (size_t)Bb * Kd * 2, stream);

  wcvt_kernel<<<dim3(16, 16, 2), 256, 0, stream>>>(Wih, Whh, WTih, WThh);
  icvt_kernel<<<(Bb * Tt * Kd) / 2048, 256, 0, stream>>>(inp, Ab);
  gemm_p_kernel<<<dim3(16, (Bb * Tt) / 64), 256, 0, stream>>>(Ab, WTih, P);
  rowscale_kernel<<<Bb * Tt, 256, 0, stream>>>(inp, P, pn2);
  rnn_kernel<<<256, 256, 0, stream>>>(hbuf, mx, WThh, P, pn2, bh,
                                      (float*)d_out, cnt);
}

// Round 3
// 3778.952 us; speedup vs baseline: 3.0138x; 3.0138x over previous
//
#include <hip/hip_runtime.h>

#define EPSF 1e-6f
#define ONEM 0.999999f
#define Bb 256
#define Tt 128
#define Kd 1024

typedef __attribute__((ext_vector_type(8))) short s16x8;
typedef __attribute__((ext_vector_type(4))) short s16x4;
typedef __attribute__((ext_vector_type(4))) float f32x4;

__device__ __forceinline__ short f2bf(float f) {
  unsigned u = __float_as_uint(f);
  u += 0x7fffu + ((u >> 16) & 1u);
  return (short)(u >> 16);
}
__device__ __forceinline__ float bf2f(short s) {
  return __uint_as_float(((unsigned)(unsigned short)s) << 16);
}
// fast tanh/atanh via hw exp/log; abs err ~1e-7 (budget 1.85e-3)
__device__ __forceinline__ float ftanh(float x) {
  float e = __expf(2.f * x);
  return 1.f - 2.f / (e + 1.f);
}
__device__ __forceinline__ float fatanh(float x) {
  return 0.5f * __logf((1.f + x) / (1.f - x));
}

// block-wide sum over 256 threads (rowscale only)
__device__ __forceinline__ float brsum(float v) {
  __shared__ float sb[4];
#pragma unroll
  for (int m = 32; m >= 1; m >>= 1) v += __shfl_xor(v, m, 64);
  __syncthreads();
  if ((threadIdx.x & 63) == 0) sb[threadIdx.x >> 6] = v;
  __syncthreads();
  return sb[0] + sb[1] + sb[2] + sb[3];
}

// ---- transpose+convert W_ih (f32 [k][n]) -> WT bf16 [n][k] (for gemm_p)
__global__ void wcvt_kernel(const float* __restrict__ W, short* __restrict__ WT) {
  __shared__ float tile[64][65];
  const int k0 = blockIdx.y * 64, n0 = blockIdx.x * 64;
  const int t = threadIdx.x;
#pragma unroll
  for (int i = 0; i < 16; i++) {
    int e = i * 256 + t, r = e >> 6, c = e & 63;
    tile[r][c] = W[(k0 + r) * Kd + n0 + c];
  }
  __syncthreads();
#pragma unroll
  for (int i = 0; i < 16; i++) {
    int e = i * 256 + t, rn = e >> 6, ck = e & 63;
    WT[(n0 + rn) * Kd + k0 + ck] = f2bf(tile[ck][rn]);
  }
}

// ---- convert W_hh into MFMA-B fragment layout:
// Wf[((nt*32+kt)*64 + l)*8 + j] = W[k][n], k=kt*32+(l>>4)*8+j, n=nt*16+(l&15)
__global__ void wfrag_kernel(const float* __restrict__ W, short* __restrict__ Wf) {
  const int bid = blockIdx.x;  // nt*32 + kt, 2048 total
  const int nn = threadIdx.x & 15, kk = threadIdx.x >> 4;  // kk 0..15
  const int l = (kk >> 2) * 16 + nn;
  const int jj = (kk & 3) * 2;
  const int nt = bid >> 5, kt = bid & 31;
  const int n = nt * 16 + nn;
  const int k = kt * 32 + (kk >> 2) * 8 + jj;
  unsigned lo = (unsigned)(unsigned short)f2bf(W[(size_t)k * Kd + n]);
  unsigned hi = (unsigned)(unsigned short)f2bf(W[(size_t)(k + 1) * Kd + n]);
  ((unsigned*)Wf)[((size_t)bid * 64 + l) * 4 + (jj >> 1)] = lo | (hi << 16);
}

// ---- convert inp f32 -> bf16
__global__ void icvt_kernel(const float* __restrict__ inp, short* __restrict__ out) {
  int i = blockIdx.x * 2048 + threadIdx.x * 8;
  float4 a = *(const float4*)(inp + i);
  float4 b = *(const float4*)(inp + i + 4);
  s16x8 v;
  v[0] = f2bf(a.x); v[1] = f2bf(a.y); v[2] = f2bf(a.z); v[3] = f2bf(a.w);
  v[4] = f2bf(b.x); v[5] = f2bf(b.y); v[6] = f2bf(b.z); v[7] = f2bf(b.w);
  *(s16x8*)(out + i) = v;
}

// ---- P_raw = inp_bf16 @ W_ih (unchanged from passing round)
__global__ void __launch_bounds__(256) gemm_p_kernel(const short* __restrict__ A,
                                                     const short* __restrict__ BT,
                                                     short* __restrict__ C) {
  const int n0 = blockIdx.x * 64, m0 = blockIdx.y * 64;
  const int tid = threadIdx.x, w = tid >> 6, l = tid & 63, lm = l & 15, q = l >> 4;
  const short* ap = A + (m0 + w * 16 + lm) * Kd + q * 8;
  const short* bp = BT + (n0 + lm) * Kd + q * 8;
  f32x4 acc0 = {0.f, 0.f, 0.f, 0.f}, acc1 = acc0, acc2 = acc0, acc3 = acc0;
#pragma unroll 4
  for (int k = 0; k < Kd; k += 32) {
    s16x8 a = *(const s16x8*)(ap + k);
    s16x8 b0 = *(const s16x8*)(bp + k);
    s16x8 b1 = *(const s16x8*)(bp + 16 * Kd + k);
    s16x8 b2 = *(const s16x8*)(bp + 32 * Kd + k);
    s16x8 b3 = *(const s16x8*)(bp + 48 * Kd + k);
    acc0 = __builtin_amdgcn_mfma_f32_16x16x32_bf16(a, b0, acc0, 0, 0, 0);
    acc1 = __builtin_amdgcn_mfma_f32_16x16x32_bf16(a, b1, acc1, 0, 0, 0);
    acc2 = __builtin_amdgcn_mfma_f32_16x16x32_bf16(a, b2, acc2, 0, 0, 0);
    acc3 = __builtin_amdgcn_mfma_f32_16x16x32_bf16(a, b3, acc3, 0, 0, 0);
  }
  const int row = m0 + w * 16 + q * 4, col = n0 + lm;
#pragma unroll
  for (int r = 0; r < 4; r++) {
    C[(row + r) * Kd + col] = f2bf(acc0[r]);
    C[(row + r) * Kd + col + 16] = f2bf(acc1[r]);
    C[(row + r) * Kd + col + 32] = f2bf(acc2[r]);
    C[(row + r) * Kd + col + 48] = f2bf(acc3[r]);
  }
}

// ---- per-row mobius_matvec scaling of P (in place), store pn2 (unchanged)
__global__ void __launch_bounds__(256) rowscale_kernel(const float* __restrict__ inp,
                                                       short* __restrict__ P,
                                                       float* __restrict__ pn2) {
  const int r = blockIdx.x, tid = threadIdx.x, i0 = tid * 4;
  float4 xv = *(const float4*)(inp + r * Kd + i0);
  float xn2 = brsum(xv.x * xv.x + xv.y * xv.y + xv.z * xv.z + xv.w * xv.w);
  s16x4 pr = *(const s16x4*)(P + r * Kd + i0);
  float p0 = bf2f(pr[0]), p1 = bf2f(pr[1]), p2 = bf2f(pr[2]), p3 = bf2f(pr[3]);
  float mxn2 = brsum(p0 * p0 + p1 * p1 + p2 * p2 + p3 * p3);
  float xn = fmaxf(sqrtf(xn2), EPSF);
  float mxn = fmaxf(sqrtf(mxn2), EPSF);
  float sc = tanhf(mxn / xn * atanhf(fminf(xn, ONEM))) / mxn;
  s16x4 po;
  po[0] = f2bf(sc * p0); po[1] = f2bf(sc * p1);
  po[2] = f2bf(sc * p2); po[3] = f2bf(sc * p3);
  *(s16x4*)(P + r * Kd + i0) = po;
  if (tid == 0) pn2[r] = sc * sc * mxn2;
}

// block-internal cross-wave row reduction: v[r] for rows q*4+r
__device__ __forceinline__ void redrows(float v[4], float rps[4][16], int w,
                                        int q, int lm) {
#pragma unroll
  for (int r = 0; r < 4; r++) {
#pragma unroll
    for (int m = 8; m >= 1; m >>= 1) v[r] += __shfl_xor(v[r], m, 64);
  }
  if (lm == 0) {
#pragma unroll
    for (int r = 0; r < 4; r++) rps[w][q * 4 + r] = v[r];
  }
  __syncthreads();
#pragma unroll
  for (int r = 0; r < 4; r++)
    v[r] = rps[0][q * 4 + r] + rps[1][q * 4 + r] + rps[2][q * 4 + r] +
           rps[3][q * 4 + r];
}

// ---- phase 2: 16 independent persistent blocks, 16 batch rows each, NO grid sync
__global__ void __launch_bounds__(256) rnn_kernel(const short* __restrict__ Wf,
                                                  const short* __restrict__ P,
                                                  const float* __restrict__ pn2,
                                                  const float* __restrict__ bh,
                                                  float* __restrict__ out) {
  __shared__ short hl[16][1032];     // h rows, bf16 (A-fragment source)
  __shared__ float rp[8][4][16];     // reduction exchange slots
  const int tid = threadIdx.x;
  const int w = tid >> 6, l = tid & 63, lm = l & 15, q = l >> 4;
  const int gr0 = blockIdx.x * 16;

  // zero h
  for (int i = tid; i < 16 * 1032 / 2; i += 256) ((int*)hl)[i] = 0;

  // per-lane bias columns: col(n) = w*256 + n*16 + lm
  float bb[16];
#pragma unroll
  for (int n = 0; n < 16; n++) bb[n] = bh[w * 256 + n * 16 + lm];
  float b2p = 0.f;
#pragma unroll
  for (int n = 0; n < 16; n++) b2p += bb[n] * bb[n];
  if (q != 0) b2p = 0.f;  // count each col once
#pragma unroll
  for (int m = 32; m >= 1; m >>= 1) b2p += __shfl_xor(b2p, m, 64);
  __syncthreads();  // hl zero visible
  if (l == 0) rp[7][w][0] = b2p;
  __syncthreads();
  const float b2 = rp[7][0][0] + rp[7][1][0] + rp[7][2][0] + rp[7][3][0];

  const short* hp = &hl[0][0] + lm * 1032 + q * 8;           // A-frag base
  const short* wp = Wf + (size_t)(w * 16) * 32 * 512 + l * 8;  // B-frag base

  float hn2c[4] = {0.f, 0.f, 0.f, 0.f};  // carried ||h||^2 per row

  for (int t = 0; t < Tt; t++) {
    // ---- GEMM: acc = h @ W_hh  (16 x 1024, K=1024); wave w -> cols w*256..+255
    f32x4 acc[16];
#pragma unroll
    for (int n = 0; n < 16; n++) acc[n] = (f32x4){0.f, 0.f, 0.f, 0.f};
#pragma unroll 2
    for (int kt = 0; kt < 32; kt++) {
      s16x8 a = *(const s16x8*)(hp + kt * 32);
      const short* wk = wp + (size_t)kt * 512;
#pragma unroll
      for (int n = 0; n < 16; n++) {
        s16x8 b = *(const s16x8*)(wk + (size_t)n * 16384);
        acc[n] = __builtin_amdgcn_mfma_f32_16x16x32_bf16(a, b, acc[n], 0, 0, 0);
      }
    }

    // ---- mobius chain, in-register C-layout (lane holds rows q*4+r, 16 cols)
    float v0[4], v1[4];
    // R1: mxn2
#pragma unroll
    for (int r = 0; r < 4; r++) {
      float s = 0.f;
#pragma unroll
      for (int n = 0; n < 16; n++) s += acc[n][r] * acc[n][r];
      v0[r] = s;
    }
    redrows(v0, rp[0], w, q, lm);
    float sc[4], x2v[4];
#pragma unroll
    for (int r = 0; r < 4; r++) {
      float hn = fmaxf(sqrtf(hn2c[r]), EPSF);
      float mxn = fmaxf(sqrtf(v0[r]), EPSF);
      sc[r] = ftanh(mxn / hn * fatanh(fminf(hn, ONEM))) / mxn;
      x2v[r] = sc[r] * sc[r] * v0[r];
    }
    // R2: xy (scale by sc after reduce)
#pragma unroll
    for (int r = 0; r < 4; r++) {
      float s = 0.f;
#pragma unroll
      for (int n = 0; n < 16; n++) s += acc[n][r] * bb[n];
      v1[r] = s;
    }
    redrows(v1, rp[1], w, q, lm);
    float ca[4], cb[4];
#pragma unroll
    for (int r = 0; r < 4; r++) {
      float xy = sc[r] * v1[r];
      float den = fmaxf(1.f + 2.f * xy + x2v[r] * b2, EPSF);
      ca[r] = (1.f + 2.f * xy + b2) / den;
      cb[r] = (1.f - x2v[r]) / den;
    }
#pragma unroll
    for (int n = 0; n < 16; n++)
#pragma unroll
      for (int r = 0; r < 4; r++)
        acc[n][r] = ca[r] * sc[r] * acc[n][r] + cb[r] * bb[n];  // acc = hv

    // load p fragment (bf16 scalars, L1/L2-hot)
    const short* pb0 = P + ((size_t)(gr0 + q * 4 + 0) * Tt + t) * Kd + w * 256 + lm;
    const short* pb1 = P + ((size_t)(gr0 + q * 4 + 1) * Tt + t) * Kd + w * 256 + lm;
    const short* pb2 = P + ((size_t)(gr0 + q * 4 + 2) * Tt + t) * Kd + w * 256 + lm;
    const short* pb3 = P + ((size_t)(gr0 + q * 4 + 3) * Tt + t) * Kd + w * 256 + lm;
    float pv[16][4];
#pragma unroll
    for (int n = 0; n < 16; n++) {
      pv[n][0] = bf2f(pb0[n * 16]);
      pv[n][1] = bf2f(pb1[n * 16]);
      pv[n][2] = bf2f(pb2[n * 16]);
      pv[n][3] = bf2f(pb3[n * 16]);
    }
    // R3: hh2 and ph
#pragma unroll
    for (int r = 0; r < 4; r++) {
      float s = 0.f, u = 0.f;
#pragma unroll
      for (int n = 0; n < 16; n++) {
        s += acc[n][r] * acc[n][r];
        u += pv[n][r] * acc[n][r];
      }
      v0[r] = s; v1[r] = u;
    }
    redrows(v0, rp[2], w, q, lm);
    redrows(v1, rp[3], w, q, lm);
    float c1[4], c2[4];
#pragma unroll
    for (int r = 0; r < 4; r++) {
      float p2s = pn2[(size_t)(gr0 + q * 4 + r) * Tt + t];
      float den2 = fmaxf(1.f + 2.f * v1[r] + p2s * v0[r], EPSF);
      c1[r] = (1.f + 2.f * v1[r] + v0[r]) / den2;
      c2[r] = (1.f - p2s) / den2;
    }
#pragma unroll
    for (int n = 0; n < 16; n++)
#pragma unroll
      for (int r = 0; r < 4; r++)
        acc[n][r] = c1[r] * pv[n][r] + c2[r] * acc[n][r];  // acc = z
    // R4: z2
#pragma unroll
    for (int r = 0; r < 4; r++) {
      float s = 0.f;
#pragma unroll
      for (int n = 0; n < 16; n++) s += acc[n][r] * acc[n][r];
      v0[r] = s;
    }
    redrows(v0, rp[4], w, q, lm);
    float g[4];
#pragma unroll
    for (int r = 0; r < 4; r++) {
      float zn = fmaxf(sqrtf(v0[r]), EPSF);
      g[r] = fatanh(fminf(zn, ONEM)) / zn;
    }
#pragma unroll
    for (int n = 0; n < 16; n++)
#pragma unroll
      for (int r = 0; r < 4; r++) acc[n][r] = ftanh(g[r] * acc[n][r]);  // acc = u
    // R5: u2
#pragma unroll
    for (int r = 0; r < 4; r++) {
      float s = 0.f;
#pragma unroll
      for (int n = 0; n < 16; n++) s += acc[n][r] * acc[n][r];
      v0[r] = s;
    }
    redrows(v0, rp[5], w, q, lm);
    float s2[4];
#pragma unroll
    for (int r = 0; r < 4; r++) {
      float un = fmaxf(sqrtf(v0[r]), EPSF);
      s2[r] = ftanh(un) / un;
      hn2c[r] = s2[r] * s2[r] * v0[r];
    }
    // write h (bf16 -> LDS); final step also writes out (f32)
#pragma unroll
    for (int r = 0; r < 4; r++) {
      short* hrow = &hl[q * 4 + r][w * 256 + lm];
      float* orow = out + (size_t)(gr0 + q * 4 + r) * Kd + w * 256 + lm;
#pragma unroll
      for (int n = 0; n < 16; n++) {
        float hvv = s2[r] * acc[n][r];
        hrow[n * 16] = f2bf(hvv);
        if (t == Tt - 1) orow[n * 16] = hvv;
      }
    }
    __syncthreads();  // h ready for next step's GEMM
  }
}

extern "C" void kernel_launch(void* const* d_in, const int* in_sizes, int n_in,
                              void* d_out, int out_size, void* d_ws, size_t ws_size,
                              hipStream_t stream) {
  const float* inp = (const float*)d_in[0];  // [256][128][1024]
  const float* Wih = (const float*)d_in[1];  // [1024][1024]
  const float* Whh = (const float*)d_in[2];  // [1024][1024]
  const float* bh = (const float*)d_in[3];   // [1024]

  char* ws = (char*)d_ws;
  size_t off = 0;
  float* pn2 = (float*)(ws + off); off += (size_t)Bb * Tt * 4;      // 128KB
  short* WTih = (short*)(ws + off); off += (size_t)Kd * Kd * 2;     // 2MB
  short* Wfhh = (short*)(ws + off); off += (size_t)Kd * Kd * 2;     // 2MB
  short* Ab = (short*)(ws + off); off += (size_t)Bb * Tt * Kd * 2;  // 64MB
  short* P = (short*)(ws + off); off += (size_t)Bb * Tt * Kd * 2;   // 64MB

  wcvt_kernel<<<dim3(16, 16), 256, 0, stream>>>(Wih, WTih);
  wfrag_kernel<<<2048, 256, 0, stream>>>(Whh, Wfhh);
  icvt_kernel<<<(Bb * Tt * Kd) / 2048, 256, 0, stream>>>(inp, Ab);
  gemm_p_kernel<<<dim3(16, (Bb * Tt) / 64), 256, 0, stream>>>(Ab, WTih, P);
  rowscale_kernel<<<Bb * Tt, 256, 0, stream>>>(inp, P, pn2);
  rnn_kernel<<<16, 256, 0, stream>>>(Wfhh, P, pn2, bh, (float*)d_out);
}

// Round 4
// 3531.026 us; speedup vs baseline: 3.2254x; 1.0702x over previous
//
#include <hip/hip_runtime.h>

#define EPSF 1e-6f
#define ONEM 0.999999f
#define Bb 256
#define Tt 128
#define Kd 1024

typedef __attribute__((ext_vector_type(8))) short s16x8;
typedef __attribute__((ext_vector_type(4))) short s16x4;
typedef __attribute__((ext_vector_type(4))) float f32x4;

__device__ __forceinline__ short f2bf(float f) {
  unsigned u = __float_as_uint(f);
  u += 0x7fffu + ((u >> 16) & 1u);
  return (short)(u >> 16);
}
__device__ __forceinline__ float bf2f(short s) {
  return __uint_as_float(((unsigned)(unsigned short)s) << 16);
}
// fast tanh/atanh via hw exp/log; abs err ~1e-7 (budget 1.85e-3)
__device__ __forceinline__ float ftanh(float x) {
  float e = __expf(2.f * x);
  return 1.f - 2.f / (e + 1.f);
}
__device__ __forceinline__ float fatanh(float x) {
  return 0.5f * __logf((1.f + x) / (1.f - x));
}
// sum over the 16 lanes of one lm-group (lanes l, l^1.., within l&~15)
__device__ __forceinline__ float red16(float v) {
#pragma unroll
  for (int m = 8; m >= 1; m >>= 1) v += __shfl_xor(v, m, 64);
  return v;
}

// block-wide sum over 256 threads (setup kernels only)
__device__ __forceinline__ float brsum(float v) {
  __shared__ float sb[4];
#pragma unroll
  for (int m = 32; m >= 1; m >>= 1) v += __shfl_xor(v, m, 64);
  __syncthreads();
  if ((threadIdx.x & 63) == 0) sb[threadIdx.x >> 6] = v;
  __syncthreads();
  return sb[0] + sb[1] + sb[2] + sb[3];
}

// 16-arrival group barrier; per-step counter pre-zeroed, target 16.
__device__ __forceinline__ void gbar16(int* c) {
  __syncthreads();  // all waves' stores/atomics vmcnt-drained before release
  if (threadIdx.x == 0) {
    __hip_atomic_fetch_add(c, 1, __ATOMIC_RELEASE, __HIP_MEMORY_SCOPE_AGENT);
    while (__hip_atomic_load(c, __ATOMIC_RELAXED, __HIP_MEMORY_SCOPE_AGENT) < 16)
      __builtin_amdgcn_s_sleep(1);
    (void)__hip_atomic_load(c, __ATOMIC_ACQUIRE, __HIP_MEMORY_SCOPE_AGENT);
  }
  __syncthreads();
}

// ---- transpose+convert W_ih (f32 [k][n]) -> WT bf16 [n][k] (for gemm_p)
__global__ void wcvt_kernel(const float* __restrict__ W, short* __restrict__ WT) {
  __shared__ float tile[64][65];
  const int k0 = blockIdx.y * 64, n0 = blockIdx.x * 64;
  const int t = threadIdx.x;
#pragma unroll
  for (int i = 0; i < 16; i++) {
    int e = i * 256 + t, r = e >> 6, c = e & 63;
    tile[r][c] = W[(k0 + r) * Kd + n0 + c];
  }
  __syncthreads();
#pragma unroll
  for (int i = 0; i < 16; i++) {
    int e = i * 256 + t, rn = e >> 6, ck = e & 63;
    WT[(n0 + rn) * Kd + k0 + ck] = f2bf(tile[ck][rn]);
  }
}

// ---- convert W_hh into MFMA-B fragment layout:
// Wf[((nt*32+kt)*64 + l)*8 + j] = W[k][n], k=kt*32+(l>>4)*8+j, n=nt*16+(l&15)
__global__ void wfrag_kernel(const float* __restrict__ W, short* __restrict__ Wf) {
  const int bid = blockIdx.x;  // nt*32 + kt, 2048 total
  const int nn = threadIdx.x & 15, kk = threadIdx.x >> 4;  // kk 0..15
  const int l = (kk >> 2) * 16 + nn;
  const int jj = (kk & 3) * 2;
  const int nt = bid >> 5, kt = bid & 31;
  const int n = nt * 16 + nn;
  const int k = kt * 32 + (kk >> 2) * 8 + jj;
  unsigned lo = (unsigned)(unsigned short)f2bf(W[(size_t)k * Kd + n]);
  unsigned hi = (unsigned)(unsigned short)f2bf(W[(size_t)(k + 1) * Kd + n]);
  ((unsigned*)Wf)[((size_t)bid * 64 + l) * 4 + (jj >> 1)] = lo | (hi << 16);
}

// ---- convert inp f32 -> bf16
__global__ void icvt_kernel(const float* __restrict__ inp, short* __restrict__ out) {
  int i = blockIdx.x * 2048 + threadIdx.x * 8;
  float4 a = *(const float4*)(inp + i);
  float4 b = *(const float4*)(inp + i + 4);
  s16x8 v;
  v[0] = f2bf(a.x); v[1] = f2bf(a.y); v[2] = f2bf(a.z); v[3] = f2bf(a.w);
  v[4] = f2bf(b.x); v[5] = f2bf(b.y); v[6] = f2bf(b.z); v[7] = f2bf(b.w);
  *(s16x8*)(out + i) = v;
}

// ---- P_raw = inp_bf16 @ W_ih
__global__ void __launch_bounds__(256) gemm_p_kernel(const short* __restrict__ A,
                                                     const short* __restrict__ BT,
                                                     short* __restrict__ C) {
  const int n0 = blockIdx.x * 64, m0 = blockIdx.y * 64;
  const int tid = threadIdx.x, w = tid >> 6, l = tid & 63, lm = l & 15, q = l >> 4;
  const short* ap = A + (m0 + w * 16 + lm) * Kd + q * 8;
  const short* bp = BT + (n0 + lm) * Kd + q * 8;
  f32x4 acc0 = {0.f, 0.f, 0.f, 0.f}, acc1 = acc0, acc2 = acc0, acc3 = acc0;
#pragma unroll 4
  for (int k = 0; k < Kd; k += 32) {
    s16x8 a = *(const s16x8*)(ap + k);
    s16x8 b0 = *(const s16x8*)(bp + k);
    s16x8 b1 = *(const s16x8*)(bp + 16 * Kd + k);
    s16x8 b2 = *(const s16x8*)(bp + 32 * Kd + k);
    s16x8 b3 = *(const s16x8*)(bp + 48 * Kd + k);
    acc0 = __builtin_amdgcn_mfma_f32_16x16x32_bf16(a, b0, acc0, 0, 0, 0);
    acc1 = __builtin_amdgcn_mfma_f32_16x16x32_bf16(a, b1, acc1, 0, 0, 0);
    acc2 = __builtin_amdgcn_mfma_f32_16x16x32_bf16(a, b2, acc2, 0, 0, 0);
    acc3 = __builtin_amdgcn_mfma_f32_16x16x32_bf16(a, b3, acc3, 0, 0, 0);
  }
  const int row = m0 + w * 16 + q * 4, col = n0 + lm;
#pragma unroll
  for (int r = 0; r < 4; r++) {
    C[(row + r) * Kd + col] = f2bf(acc0[r]);
    C[(row + r) * Kd + col + 16] = f2bf(acc1[r]);
    C[(row + r) * Kd + col + 32] = f2bf(acc2[r]);
    C[(row + r) * Kd + col + 48] = f2bf(acc3[r]);
  }
}

// ---- per-row mobius_matvec scaling of P (in place); store pn2 = ||p||^2 and
// pb2 = p.b (both on the bf16-rounded stored p, consistent with rnn's pv)
__global__ void __launch_bounds__(256) rowscale_kernel(const float* __restrict__ inp,
                                                       const float* __restrict__ bh,
                                                       short* __restrict__ P,
                                                       float* __restrict__ pn2,
                                                       float* __restrict__ pb2) {
  const int r = blockIdx.x, tid = threadIdx.x, i0 = tid * 4;
  float4 xv = *(const float4*)(inp + r * Kd + i0);
  float xn2 = brsum(xv.x * xv.x + xv.y * xv.y + xv.z * xv.z + xv.w * xv.w);
  s16x4 pr = *(const s16x4*)(P + r * Kd + i0);
  float p0 = bf2f(pr[0]), p1 = bf2f(pr[1]), p2 = bf2f(pr[2]), p3 = bf2f(pr[3]);
  float mxn2 = brsum(p0 * p0 + p1 * p1 + p2 * p2 + p3 * p3);
  float xn = fmaxf(sqrtf(xn2), EPSF);
  float mxn = fmaxf(sqrtf(mxn2), EPSF);
  float sc = tanhf(mxn / xn * atanhf(fminf(xn, ONEM))) / mxn;
  s16x4 po;
  po[0] = f2bf(sc * p0); po[1] = f2bf(sc * p1);
  po[2] = f2bf(sc * p2); po[3] = f2bf(sc * p3);
  *(s16x4*)(P + r * Kd + i0) = po;
  float4 bv = *(const float4*)(bh + i0);
  float s0 = bf2f(po[0]), s1 = bf2f(po[1]), s2v = bf2f(po[2]), s3 = bf2f(po[3]);
  float pn2v = brsum(s0 * s0 + s1 * s1 + s2v * s2v + s3 * s3);
  float pbv = brsum(s0 * bv.x + s1 * bv.y + s2v * bv.z + s3 * bv.w);
  if (tid == 0) { pn2[r] = pn2v; pb2[r] = pbv; }
}

// ---- phase 2: 256 blocks = 16 groups (16 batch rows) x 16 N-blocks (64 cols).
// W_hh slice + h(u) fragments live in REGISTERS; per step: reg-GEMM,
// cross-block dot-reduce (R1), scalar mobius algebra, tanh, cross-block
// u^2-reduce + u-exchange (R2). Two 16-arrival barriers per step.
__global__ void __launch_bounds__(256, 1) rnn_kernel(
    const short* __restrict__ Wf, const short* __restrict__ P,
    const float* __restrict__ pn2, const float* __restrict__ pb2,
    const float* __restrict__ bh, float* __restrict__ out,
    float* __restrict__ S, int* __restrict__ cnt, short* __restrict__ ubuf) {
  __shared__ float red[4][16][4];
  __shared__ float bex[4];
  const int tid = threadIdx.x, w = tid >> 6, l = tid & 63, lm = l & 15, q = l >> 4;
  const int g = blockIdx.x & 15, nb = blockIdx.x >> 4;
  const int gr0 = g * 16;
  const int c = nb * 64 + w * 16 + lm;  // my output column
  const int nt = nb * 4 + w;            // Wf 16-col tile index

  // ---- b2 = ||b||^2 (block-wide) and my bias value
  float4 bv4 = *(const float4*)(bh + tid * 4);
  float bp = bv4.x * bv4.x + bv4.y * bv4.y + bv4.z * bv4.z + bv4.w * bv4.w;
#pragma unroll
  for (int m = 32; m >= 1; m >>= 1) bp += __shfl_xor(bp, m, 64);
  if (l == 0) bex[w] = bp;
  __syncthreads();
  const float b2 = bex[0] + bex[1] + bex[2] + bex[3];
  const float bb = bh[c];

  // ---- W_hh B-fragments for my 16-col strip: 32 x 16B = 64 VGPRs
  s16x8 wfr[32];
#pragma unroll
  for (int kt = 0; kt < 32; kt++)
    wfr[kt] = *(const s16x8*)(Wf + ((size_t)(nt * 32 + kt) * 64 + l) * 8);

  // ---- u A-fragments (h = lam*u), 64 VGPRs; zero-init (h0 = 0)
  s16x8 a[32];
#pragma unroll
  for (int kt = 0; kt < 32; kt++) a[kt] = (s16x8){0, 0, 0, 0, 0, 0, 0, 0};
  float lam[4] = {1.f, 1.f, 1.f, 1.f};   // s2 of previous step per C-row
  float hn2c[4] = {0.f, 0.f, 0.f, 0.f};  // ||h||^2 per C-row

  for (int t = 0; t < Tt; t++) {
    // prefetch p and per-row precomputed dots (HBM; independent of GEMM)
    float pv[4], p2s[4], pbr[4];
#pragma unroll
    for (int r = 0; r < 4; r++) {
      size_t rt = (size_t)(gr0 + q * 4 + r) * Tt + t;
      pv[r] = bf2f(P[rt * Kd + c]);
      p2s[r] = pn2[rt];
      pbr[r] = pb2[rt];
    }

    // ---- GEMM from registers: mx_u = u @ W_hh (my 16x16 tile, K=1024)
    f32x4 c0 = {0.f, 0.f, 0.f, 0.f}, c1v = c0, c2v = c0, c3v = c0;
#pragma unroll
    for (int kt = 0; kt < 32; kt += 4) {
      c0 = __builtin_amdgcn_mfma_f32_16x16x32_bf16(a[kt], wfr[kt], c0, 0, 0, 0);
      c1v = __builtin_amdgcn_mfma_f32_16x16x32_bf16(a[kt + 1], wfr[kt + 1], c1v, 0, 0, 0);
      c2v = __builtin_amdgcn_mfma_f32_16x16x32_bf16(a[kt + 2], wfr[kt + 2], c2v, 0, 0, 0);
      c3v = __builtin_amdgcn_mfma_f32_16x16x32_bf16(a[kt + 3], wfr[kt + 3], c3v, 0, 0, 0);
    }
    f32x4 accv = (c0 + c1v) + (c2v + c3v);
    float mx[4];
#pragma unroll
    for (int r = 0; r < 4; r++) mx[r] = lam[r] * accv[r];  // true mx

    // ---- R1 partials: {mx^2, mx*b, p*mx} summed over my 16 cols
#pragma unroll
    for (int r = 0; r < 4; r++) {
      float vm2 = red16(mx[r] * mx[r]);
      float vmb = red16(mx[r] * bb);
      float vpm = red16(pv[r] * mx[r]);
      if (lm == 0) {
        red[w][q * 4 + r][0] = vm2;
        red[w][q * 4 + r][1] = vmb;
        red[w][q * 4 + r][2] = vpm;
      }
    }
    __syncthreads();
    float* Sg = S + ((size_t)t * 16 + g) * 64;  // [16 rows][4]
    if (tid < 64) {
      int row = tid >> 2, s = tid & 3;
      if (s < 3) {
        float v = red[0][row][s] + red[1][row][s] + red[2][row][s] + red[3][row][s];
        __hip_atomic_fetch_add(&Sg[row * 4 + s], v, __ATOMIC_RELAXED,
                               __HIP_MEMORY_SCOPE_AGENT);
      }
    }
    int* cg = cnt + ((size_t)t * 16 + g) * 2;
    gbar16(cg);

    // ---- scalar mobius algebra per row + elementwise z, u
    float uu[4], u2p[4];
#pragma unroll
    for (int r = 0; r < 4; r++) {
      float Smm = Sg[(q * 4 + r) * 4 + 0];
      float Smb = Sg[(q * 4 + r) * 4 + 1];
      float Spm = Sg[(q * 4 + r) * 4 + 2];
      float hn = fmaxf(sqrtf(hn2c[r]), EPSF);
      float mxn = fmaxf(sqrtf(Smm), EPSF);
      float sc = ftanh(mxn / hn * fatanh(fminf(hn, ONEM))) / mxn;
      float x2 = sc * sc * Smm;
      float xy = sc * Smb;
      float den = fmaxf(1.f + 2.f * xy + x2 * b2, EPSF);
      float al = ((1.f + 2.f * xy + b2) / den) * sc;  // hv = al*mx + be*b
      float be = (1.f - x2) / den;
      float hh2 = al * al * Smm + 2.f * al * be * Smb + be * be * b2;
      float ph = al * Spm + be * pbr[r];
      float den2 = fmaxf(1.f + 2.f * ph + p2s[r] * hh2, EPSF);
      float cc1 = (1.f + 2.f * ph + hh2) / den2;
      float cc2 = (1.f - p2s[r]) / den2;
      float z = cc1 * pv[r] + cc2 * (al * mx[r] + be * bb);
      float z2 = cc1 * cc1 * p2s[r] + cc2 * cc2 * hh2 + 2.f * cc1 * cc2 * ph;
      float zn = fmaxf(sqrtf(z2), EPSF);
      float gg = fatanh(fminf(zn, ONEM)) / zn;
      uu[r] = ftanh(gg * z);
      u2p[r] = red16(uu[r] * uu[r]);
    }

    // ---- R2: write u slice + u^2 partial, barrier, then s2 & rebuild frags
    const int p = t & 1;
    short* ub = ubuf + ((size_t)(p * 16 + g) * 16) * Kd;
#pragma unroll
    for (int r = 0; r < 4; r++) {
      ub[(q * 4 + r) * Kd + c] = f2bf(uu[r]);
      if (lm == 0) red[w][q * 4 + r][3] = u2p[r];
    }
    __syncthreads();
    if (tid < 16) {
      float v = red[0][tid][3] + red[1][tid][3] + red[2][tid][3] + red[3][tid][3];
      __hip_atomic_fetch_add(&Sg[tid * 4 + 3], v, __ATOMIC_RELAXED,
                             __HIP_MEMORY_SCOPE_AGENT);
    }
    gbar16(cg + 1);

#pragma unroll
    for (int r = 0; r < 4; r++) {
      float u2 = Sg[(q * 4 + r) * 4 + 3];
      float un = fmaxf(sqrtf(u2), EPSF);
      float s2 = ftanh(un) / un;
      lam[r] = s2;
      hn2c[r] = s2 * s2 * u2;
      if (t == Tt - 1)
        out[(size_t)(gr0 + q * 4 + r) * Kd + c] = s2 * uu[r];
    }
    // rebuild u A-fragments: row = lm (A-role), k = kt*32 + q*8 + j
    const short* ur = ub + lm * Kd + q * 8;
#pragma unroll
    for (int kt = 0; kt < 32; kt++) a[kt] = *(const s16x8*)(ur + kt * 32);
  }
}

extern "C" void kernel_launch(void* const* d_in, const int* in_sizes, int n_in,
                              void* d_out, int out_size, void* d_ws, size_t ws_size,
                              hipStream_t stream) {
  const float* inp = (const float*)d_in[0];  // [256][128][1024]
  const float* Wih = (const float*)d_in[1];  // [1024][1024]
  const float* Whh = (const float*)d_in[2];  // [1024][1024]
  const float* bh = (const float*)d_in[3];   // [1024]

  char* ws = (char*)d_ws;
  size_t off = 0;
  float* S = (float*)(ws + off); off += (size_t)Tt * 16 * 16 * 4 * 4;   // 512KB
  int* cnt = (int*)(ws + off); off += (size_t)Tt * 16 * 2 * 4;          // 16KB
  size_t zbytes = off;                                                  // memset
  short* ubuf = (short*)(ws + off); off += (size_t)2 * 16 * 16 * Kd * 2; // 1MB
  float* pn2 = (float*)(ws + off); off += (size_t)Bb * Tt * 4;          // 128KB
  float* pb2 = (float*)(ws + off); off += (size_t)Bb * Tt * 4;          // 128KB
  short* WTih = (short*)(ws + off); off += (size_t)Kd * Kd * 2;         // 2MB
  short* Wfhh = (short*)(ws + off); off += (size_t)Kd * Kd * 2;         // 2MB
  short* Ab = (short*)(ws + off); off += (size_t)Bb * Tt * Kd * 2;      // 64MB
  short* P = (short*)(ws + off); off += (size_t)Bb * Tt * Kd * 2;       // 64MB

  hipMemsetAsync(d_ws, 0, zbytes, stream);  // S sums + counters

  wcvt_kernel<<<dim3(16, 16), 256, 0, stream>>>(Wih, WTih);
  wfrag_kernel<<<2048, 256, 0, stream>>>(Whh, Wfhh);
  icvt_kernel<<<(Bb * Tt * Kd) / 2048, 256, 0, stream>>>(inp, Ab);
  gemm_p_kernel<<<dim3(16, (Bb * Tt) / 64), 256, 0, stream>>>(Ab, WTih, P);
  rowscale_kernel<<<Bb * Tt, 256, 0, stream>>>(inp, bh, P, pn2, pb2);
  rnn_kernel<<<256, 256, 0, stream>>>(Wfhh, P, pn2, pb2, bh, (float*)d_out,
                                      S, cnt, ubuf);
}

// Round 5
// 2546.286 us; speedup vs baseline: 4.4728x; 1.3867x over previous
//
#include <hip/hip_runtime.h>

#define EPSF 1e-6f
#define ONEM 0.999999f
#define Bb 256
#define Tt 128
#define Kd 1024

typedef __attribute__((ext_vector_type(8))) short s16x8;
typedef __attribute__((ext_vector_type(4))) short s16x4;
typedef __attribute__((ext_vector_type(4))) float f32x4;
typedef unsigned long long ull;

union U8 { ull u; s16x4 v; };
union PF { ull u; float f[2]; };

__device__ __forceinline__ short f2bf(float f) {
  unsigned u = __float_as_uint(f);
  u += 0x7fffu + ((u >> 16) & 1u);
  return (short)(u >> 16);
}
__device__ __forceinline__ float bf2f(short s) {
  return __uint_as_float(((unsigned)(unsigned short)s) << 16);
}
// fast tanh/atanh via hw exp/log; abs err ~1e-7 (budget 1.85e-3)
__device__ __forceinline__ float ftanh(float x) {
  float e = __expf(2.f * x);
  return 1.f - 2.f / (e + 1.f);
}
__device__ __forceinline__ float fatanh(float x) {
  return 0.5f * __logf((1.f + x) / (1.f - x));
}
// sum over the 16 lanes of one lm-group
__device__ __forceinline__ float red16(float v) {
#pragma unroll
  for (int m = 8; m >= 1; m >>= 1) v += __shfl_xor(v, m, 64);
  return v;
}

// block-wide sum over 256 threads (setup kernels only)
__device__ __forceinline__ float brsum(float v) {
  __shared__ float sb[4];
#pragma unroll
  for (int m = 32; m >= 1; m >>= 1) v += __shfl_xor(v, m, 64);
  __syncthreads();
  if ((threadIdx.x & 63) == 0) sb[threadIdx.x >> 6] = v;
  __syncthreads();
  return sb[0] + sb[1] + sb[2] + sb[3];
}

// 16-arrival barrier, ALL RELAXED (no wbl2/inv cache ops). Ordering comes
// from __syncthreads' vmcnt(0) drain: my data-atomics are LLC-complete
// before my flag add issues; consumers read data with bypassing atomics.
__device__ __forceinline__ void gbarR(int* c) {
  __syncthreads();
  if (threadIdx.x == 0) {
    __hip_atomic_fetch_add(c, 1, __ATOMIC_RELAXED, __HIP_MEMORY_SCOPE_AGENT);
    while (__hip_atomic_load(c, __ATOMIC_RELAXED, __HIP_MEMORY_SCOPE_AGENT) < 16)
      __builtin_amdgcn_s_sleep(1);
  }
  __syncthreads();
}

// ---- transpose+convert W_ih (f32 [k][n]) -> WT bf16 [n][k] (for gemm_p)
__global__ void wcvt_kernel(const float* __restrict__ W, short* __restrict__ WT) {
  __shared__ float tile[64][65];
  const int k0 = blockIdx.y * 64, n0 = blockIdx.x * 64;
  const int t = threadIdx.x;
#pragma unroll
  for (int i = 0; i < 16; i++) {
    int e = i * 256 + t, r = e >> 6, c = e & 63;
    tile[r][c] = W[(k0 + r) * Kd + n0 + c];
  }
  __syncthreads();
#pragma unroll
  for (int i = 0; i < 16; i++) {
    int e = i * 256 + t, rn = e >> 6, ck = e & 63;
    WT[(n0 + rn) * Kd + k0 + ck] = f2bf(tile[ck][rn]);
  }
}

// ---- convert W_hh into MFMA-B fragment layout
__global__ void wfrag_kernel(const float* __restrict__ W, short* __restrict__ Wf) {
  const int bid = blockIdx.x;  // nt*32 + kt
  const int nn = threadIdx.x & 15, kk = threadIdx.x >> 4;
  const int l = (kk >> 2) * 16 + nn;
  const int jj = (kk & 3) * 2;
  const int nt = bid >> 5, kt = bid & 31;
  const int n = nt * 16 + nn;
  const int k = kt * 32 + (kk >> 2) * 8 + jj;
  unsigned lo = (unsigned)(unsigned short)f2bf(W[(size_t)k * Kd + n]);
  unsigned hi = (unsigned)(unsigned short)f2bf(W[(size_t)(k + 1) * Kd + n]);
  ((unsigned*)Wf)[((size_t)bid * 64 + l) * 4 + (jj >> 1)] = lo | (hi << 16);
}

// ---- convert inp f32 -> bf16
__global__ void icvt_kernel(const float* __restrict__ inp, short* __restrict__ out) {
  int i = blockIdx.x * 2048 + threadIdx.x * 8;
  float4 a = *(const float4*)(inp + i);
  float4 b = *(const float4*)(inp + i + 4);
  s16x8 v;
  v[0] = f2bf(a.x); v[1] = f2bf(a.y); v[2] = f2bf(a.z); v[3] = f2bf(a.w);
  v[4] = f2bf(b.x); v[5] = f2bf(b.y); v[6] = f2bf(b.z); v[7] = f2bf(b.w);
  *(s16x8*)(out + i) = v;
}

// ---- P_raw = inp_bf16 @ W_ih
__global__ void __launch_bounds__(256) gemm_p_kernel(const short* __restrict__ A,
                                                     const short* __restrict__ BT,
                                                     short* __restrict__ C) {
  const int n0 = blockIdx.x * 64, m0 = blockIdx.y * 64;
  const int tid = threadIdx.x, w = tid >> 6, l = tid & 63, lm = l & 15, q = l >> 4;
  const short* ap = A + (m0 + w * 16 + lm) * Kd + q * 8;
  const short* bp = BT + (n0 + lm) * Kd + q * 8;
  f32x4 acc0 = {0.f, 0.f, 0.f, 0.f}, acc1 = acc0, acc2 = acc0, acc3 = acc0;
#pragma unroll 4
  for (int k = 0; k < Kd; k += 32) {
    s16x8 a = *(const s16x8*)(ap + k);
    s16x8 b0 = *(const s16x8*)(bp + k);
    s16x8 b1 = *(const s16x8*)(bp + 16 * Kd + k);
    s16x8 b2 = *(const s16x8*)(bp + 32 * Kd + k);
    s16x8 b3 = *(const s16x8*)(bp + 48 * Kd + k);
    acc0 = __builtin_amdgcn_mfma_f32_16x16x32_bf16(a, b0, acc0, 0, 0, 0);
    acc1 = __builtin_amdgcn_mfma_f32_16x16x32_bf16(a, b1, acc1, 0, 0, 0);
    acc2 = __builtin_amdgcn_mfma_f32_16x16x32_bf16(a, b2, acc2, 0, 0, 0);
    acc3 = __builtin_amdgcn_mfma_f32_16x16x32_bf16(a, b3, acc3, 0, 0, 0);
  }
  const int row = m0 + w * 16 + q * 4, col = n0 + lm;
#pragma unroll
  for (int r = 0; r < 4; r++) {
    C[(row + r) * Kd + col] = f2bf(acc0[r]);
    C[(row + r) * Kd + col + 16] = f2bf(acc1[r]);
    C[(row + r) * Kd + col + 32] = f2bf(acc2[r]);
    C[(row + r) * Kd + col + 48] = f2bf(acc3[r]);
  }
}

// ---- per-row mobius_matvec scaling of P; store pn2 = ||p||^2, pb2 = p.b
__global__ void __launch_bounds__(256) rowscale_kernel(const float* __restrict__ inp,
                                                       const float* __restrict__ bh,
                                                       short* __restrict__ P,
                                                       float* __restrict__ pn2,
                                                       float* __restrict__ pb2) {
  const int r = blockIdx.x, tid = threadIdx.x, i0 = tid * 4;
  float4 xv = *(const float4*)(inp + r * Kd + i0);
  float xn2 = brsum(xv.x * xv.x + xv.y * xv.y + xv.z * xv.z + xv.w * xv.w);
  s16x4 pr = *(const s16x4*)(P + r * Kd + i0);
  float p0 = bf2f(pr[0]), p1 = bf2f(pr[1]), p2 = bf2f(pr[2]), p3 = bf2f(pr[3]);
  float mxn2 = brsum(p0 * p0 + p1 * p1 + p2 * p2 + p3 * p3);
  float xn = fmaxf(sqrtf(xn2), EPSF);
  float mxn = fmaxf(sqrtf(mxn2), EPSF);
  float sc = tanhf(mxn / xn * atanhf(fminf(xn, ONEM))) / mxn;
  s16x4 po;
  po[0] = f2bf(sc * p0); po[1] = f2bf(sc * p1);
  po[2] = f2bf(sc * p2); po[3] = f2bf(sc * p3);
  *(s16x4*)(P + r * Kd + i0) = po;
  float4 bv = *(const float4*)(bh + i0);
  float s0 = bf2f(po[0]), s1 = bf2f(po[1]), s2v = bf2f(po[2]), s3 = bf2f(po[3]);
  float pn2v = brsum(s0 * s0 + s1 * s1 + s2v * s2v + s3 * s3);
  float pbv = brsum(s0 * bv.x + s1 * bv.y + s2v * bv.z + s3 * bv.w);
  if (tid == 0) { pn2[r] = pn2v; pb2[r] = pbv; }
}

// ---- phase 2: 256 blocks = 16 groups x 16 N-blocks; W_hh slice in registers;
// all cross-block traffic via RELAXED agent atomics (LLC), no cache ops.
__global__ void __launch_bounds__(256, 1) rnn_kernel(
    const short* __restrict__ Wf, const short* __restrict__ P,
    const float* __restrict__ pn2, const float* __restrict__ pb2,
    const float* __restrict__ bh, float* __restrict__ out,
    float* __restrict__ S, int* __restrict__ cnt, ull* __restrict__ ubuf) {
  __shared__ float red[4][16][4];
  __shared__ float bex[4];
  const int tid = threadIdx.x, w = tid >> 6, l = tid & 63, lm = l & 15, q = l >> 4;
  const int g = blockIdx.x & 15, nb = blockIdx.x >> 4;
  const int gr0 = g * 16;
  const int c = nb * 64 + w * 16 + lm;  // my output column
  const int nt = nb * 4 + w;            // Wf 16-col tile index

  // ---- b2 = ||b||^2 (block-wide) and my bias value
  float4 bv4 = *(const float4*)(bh + tid * 4);
  float bp = bv4.x * bv4.x + bv4.y * bv4.y + bv4.z * bv4.z + bv4.w * bv4.w;
#pragma unroll
  for (int m = 32; m >= 1; m >>= 1) bp += __shfl_xor(bp, m, 64);
  if (l == 0) bex[w] = bp;
  __syncthreads();
  const float b2 = bex[0] + bex[1] + bex[2] + bex[3];
  const float bb = bh[c];

  // ---- W_hh B-fragments for my 16-col strip: 32 x 16B = 128 VGPRs
  s16x8 wfr[32];
#pragma unroll
  for (int kt = 0; kt < 32; kt++)
    wfr[kt] = *(const s16x8*)(Wf + ((size_t)(nt * 32 + kt) * 64 + l) * 8);

  // ---- u A-fragments (h = lam*u); zero-init (h0 = 0)
  s16x8 a[32];
#pragma unroll
  for (int kt = 0; kt < 32; kt++) a[kt] = (s16x8){0, 0, 0, 0, 0, 0, 0, 0};
  float lam[4] = {1.f, 1.f, 1.f, 1.f};
  float hn2c[4] = {0.f, 0.f, 0.f, 0.f};

  for (int t = 0; t < Tt; t++) {
    // prefetch p and per-row precomputed dots (plain loads: read-only inputs)
    float pv[4], p2s[4], pbr[4];
#pragma unroll
    for (int r = 0; r < 4; r++) {
      size_t rt = (size_t)(gr0 + q * 4 + r) * Tt + t;
      pv[r] = bf2f(P[rt * Kd + c]);
      p2s[r] = pn2[rt];
      pbr[r] = pb2[rt];
    }

    // ---- GEMM from registers: u @ W_hh (my 16x16 tile, K=1024)
    f32x4 c0 = {0.f, 0.f, 0.f, 0.f}, c1v = c0, c2v = c0, c3v = c0;
#pragma unroll
    for (int kt = 0; kt < 32; kt += 4) {
      c0 = __builtin_amdgcn_mfma_f32_16x16x32_bf16(a[kt], wfr[kt], c0, 0, 0, 0);
      c1v = __builtin_amdgcn_mfma_f32_16x16x32_bf16(a[kt + 1], wfr[kt + 1], c1v, 0, 0, 0);
      c2v = __builtin_amdgcn_mfma_f32_16x16x32_bf16(a[kt + 2], wfr[kt + 2], c2v, 0, 0, 0);
      c3v = __builtin_amdgcn_mfma_f32_16x16x32_bf16(a[kt + 3], wfr[kt + 3], c3v, 0, 0, 0);
    }
    f32x4 accv = (c0 + c1v) + (c2v + c3v);
    float mx[4];
#pragma unroll
    for (int r = 0; r < 4; r++) mx[r] = lam[r] * accv[r];

    // ---- R1 partials: {mx^2, mx*b, p*mx} over my 16 cols
#pragma unroll
    for (int r = 0; r < 4; r++) {
      float vm2 = red16(mx[r] * mx[r]);
      float vmb = red16(mx[r] * bb);
      float vpm = red16(pv[r] * mx[r]);
      if (lm == 0) {
        red[w][q * 4 + r][0] = vm2;
        red[w][q * 4 + r][1] = vmb;
        red[w][q * 4 + r][2] = vpm;
      }
    }
    __syncthreads();
    float* Sg = S + ((size_t)t * 16 + g) * 64;  // [16 rows][4]
    if (tid < 64) {
      int row = tid >> 2, s = tid & 3;
      if (s < 3) {
        float v = red[0][row][s] + red[1][row][s] + red[2][row][s] + red[3][row][s];
        __hip_atomic_fetch_add(&Sg[row * 4 + s], v, __ATOMIC_RELAXED,
                               __HIP_MEMORY_SCOPE_AGENT);
      }
    }
    int* cg = cnt + ((size_t)t * 16 + g) * 16;  // 64B line per (t,g)
    gbarR(cg);

    // ---- read dots (ATOMIC: bypass stale L1/L2), scalar mobius algebra
    float uu[4], u2p[4];
#pragma unroll
    for (int r = 0; r < 4; r++) {
      PF d01;
      d01.u = __hip_atomic_load((ull*)Sg + (q * 4 + r) * 2, __ATOMIC_RELAXED,
                                __HIP_MEMORY_SCOPE_AGENT);
      float Spm = __hip_atomic_load(&Sg[(q * 4 + r) * 4 + 2], __ATOMIC_RELAXED,
                                    __HIP_MEMORY_SCOPE_AGENT);
      float Smm = d01.f[0], Smb = d01.f[1];
      float hn = fmaxf(sqrtf(hn2c[r]), EPSF);
      float mxn = fmaxf(sqrtf(Smm), EPSF);
      float sc = ftanh(mxn / hn * fatanh(fminf(hn, ONEM))) / mxn;
      float x2 = sc * sc * Smm;
      float xy = sc * Smb;
      float den = fmaxf(1.f + 2.f * xy + x2 * b2, EPSF);
      float al = ((1.f + 2.f * xy + b2) / den) * sc;  // hv = al*mx + be*b
      float be = (1.f - x2) / den;
      float hh2 = al * al * Smm + 2.f * al * be * Smb + be * be * b2;
      float ph = al * Spm + be * pbr[r];
      float den2 = fmaxf(1.f + 2.f * ph + p2s[r] * hh2, EPSF);
      float cc1 = (1.f + 2.f * ph + hh2) / den2;
      float cc2 = (1.f - p2s[r]) / den2;
      float z = cc1 * pv[r] + cc2 * (al * mx[r] + be * bb);
      float z2 = cc1 * cc1 * p2s[r] + cc2 * cc2 * hh2 + 2.f * cc1 * cc2 * ph;
      float zn = fmaxf(sqrtf(z2), EPSF);
      float gg = fatanh(fminf(zn, ONEM)) / zn;
      uu[r] = ftanh(gg * z);
      u2p[r] = red16(uu[r] * uu[r]);
    }

    // ---- R2: u exchange (packed 4xbf16 per 8B relaxed atomic) + u^2 sums
    const int p = t & 1;
    ull* ubw = ubuf + ((size_t)(p * 16 + g) * 16) * 256;  // [16 rows][256]
    const int ent = nb * 16 + w * 4 + (lm >> 2);
#pragma unroll
    for (int r = 0; r < 4; r++) {
      unsigned v16 = (unsigned)(unsigned short)f2bf(uu[r]);
      unsigned o1 = (unsigned)__shfl_xor((int)v16, 1, 64);
      unsigned plo = v16 | (o1 << 16);             // valid on even lm
      unsigned phi = (unsigned)__shfl_xor((int)plo, 2, 64);  // from lm+2
      if ((lm & 3) == 0) {
        ull pk = (ull)plo | ((ull)phi << 32);
        __hip_atomic_store(&ubw[(q * 4 + r) * 256 + ent], pk, __ATOMIC_RELAXED,
                           __HIP_MEMORY_SCOPE_AGENT);
      }
      if (lm == 0) red[w][q * 4 + r][3] = u2p[r];
    }
    __syncthreads();
    if (tid < 16) {
      float v = red[0][tid][3] + red[1][tid][3] + red[2][tid][3] + red[3][tid][3];
      __hip_atomic_fetch_add(&Sg[tid * 4 + 3], v, __ATOMIC_RELAXED,
                             __HIP_MEMORY_SCOPE_AGENT);
    }
    gbarR(cg + 8);

#pragma unroll
    for (int r = 0; r < 4; r++) {
      float u2 = __hip_atomic_load(&Sg[(q * 4 + r) * 4 + 3], __ATOMIC_RELAXED,
                                   __HIP_MEMORY_SCOPE_AGENT);
      float un = fmaxf(sqrtf(u2), EPSF);
      float s2 = ftanh(un) / un;
      lam[r] = s2;
      hn2c[r] = s2 * s2 * u2;
      if (t == Tt - 1)
        out[(size_t)(gr0 + q * 4 + r) * Kd + c] = s2 * uu[r];
    }
    // rebuild u A-fragments (row = lm) via relaxed 8B atomic loads
    const ull* ur = ubuf + ((size_t)(p * 16 + g) * 16 + lm) * 256;
#pragma unroll
    for (int kt = 0; kt < 32; kt++) {
      U8 x, y;
      x.u = __hip_atomic_load(&ur[kt * 8 + q * 2], __ATOMIC_RELAXED,
                              __HIP_MEMORY_SCOPE_AGENT);
      y.u = __hip_atomic_load(&ur[kt * 8 + q * 2 + 1], __ATOMIC_RELAXED,
                              __HIP_MEMORY_SCOPE_AGENT);
      a[kt] = __builtin_shufflevector(x.v, y.v, 0, 1, 2, 3, 4, 5, 6, 7);
    }
  }
}

extern "C" void kernel_launch(void* const* d_in, const int* in_sizes, int n_in,
                              void* d_out, int out_size, void* d_ws, size_t ws_size,
                              hipStream_t stream) {
  const float* inp = (const float*)d_in[0];  // [256][128][1024]
  const float* Wih = (const float*)d_in[1];  // [1024][1024]
  const float* Whh = (const float*)d_in[2];  // [1024][1024]
  const float* bh = (const float*)d_in[3];   // [1024]

  char* ws = (char*)d_ws;
  size_t off = 0;
  float* S = (float*)(ws + off); off += (size_t)Tt * 16 * 64 * 4;        // 512KB
  int* cnt = (int*)(ws + off); off += (size_t)Tt * 16 * 16 * 4;          // 128KB
  size_t zbytes = off;
  ull* ubuf = (ull*)(ws + off); off += (size_t)2 * 16 * 16 * 256 * 8;    // 1MB
  float* pn2 = (float*)(ws + off); off += (size_t)Bb * Tt * 4;           // 128KB
  float* pb2 = (float*)(ws + off); off += (size_t)Bb * Tt * 4;           // 128KB
  short* WTih = (short*)(ws + off); off += (size_t)Kd * Kd * 2;          // 2MB
  short* Wfhh = (short*)(ws + off); off += (size_t)Kd * Kd * 2;          // 2MB
  short* Ab = (short*)(ws + off); off += (size_t)Bb * Tt * Kd * 2;       // 64MB
  short* P = (short*)(ws + off); off += (size_t)Bb * Tt * Kd * 2;        // 64MB

  hipMemsetAsync(d_ws, 0, zbytes, stream);  // S sums + counters

  wcvt_kernel<<<dim3(16, 16), 256, 0, stream>>>(Wih, WTih);
  wfrag_kernel<<<2048, 256, 0, stream>>>(Whh, Wfhh);
  icvt_kernel<<<(Bb * Tt * Kd) / 2048, 256, 0, stream>>>(inp, Ab);
  gemm_p_kernel<<<dim3(16, (Bb * Tt) / 64), 256, 0, stream>>>(Ab, WTih, P);
  rowscale_kernel<<<Bb * Tt, 256, 0, stream>>>(inp, bh, P, pn2, pb2);
  rnn_kernel<<<256, 256, 0, stream>>>(Wfhh, P, pn2, pb2, bh, (float*)d_out,
                                      S, cnt, ubuf);
}

// Round 7
// 2130.844 us; speedup vs baseline: 5.3449x; 1.1950x over previous
//
#include <hip/hip_runtime.h>

#define EPSF 1e-6f
#define ONEM 0.999999f
#define Bb 256
#define Tt 128
#define Kd 1024

typedef __attribute__((ext_vector_type(8))) short s16x8;
typedef __attribute__((ext_vector_type(4))) short s16x4;
typedef __attribute__((ext_vector_type(4))) float f32x4;
typedef unsigned long long ull;

union PF { ull u; float f[2]; };

__device__ __forceinline__ short f2bf(float f) {
  unsigned u = __float_as_uint(f);
  u += 0x7fffu + ((u >> 16) & 1u);
  return (short)(u >> 16);
}
__device__ __forceinline__ float bf2f(short s) {
  return __uint_as_float(((unsigned)(unsigned short)s) << 16);
}
// fast tanh/atanh via hw exp/log; abs err ~1e-7 (budget 1.85e-3)
__device__ __forceinline__ float ftanh(float x) {
  float e = __expf(2.f * x);
  return 1.f - 2.f / (e + 1.f);
}
__device__ __forceinline__ float fatanh(float x) {
  return 0.5f * __logf((1.f + x) / (1.f - x));
}
// sum over the 16 lanes of one lm-group
__device__ __forceinline__ float red16(float v) {
#pragma unroll
  for (int m = 8; m >= 1; m >>= 1) v += __shfl_xor(v, m, 64);
  return v;
}

// block-wide sum over 256 threads (setup kernels only)
__device__ __forceinline__ float brsum(float v) {
  __shared__ float sb[4];
#pragma unroll
  for (int m = 32; m >= 1; m >>= 1) v += __shfl_xor(v, m, 64);
  __syncthreads();
  if ((threadIdx.x & 63) == 0) sb[threadIdx.x >> 6] = v;
  __syncthreads();
  return sb[0] + sb[1] + sb[2] + sb[3];
}

// 16-arrival barrier, ALL RELAXED (no wbl2/inv cache ops). Ordering comes
// from __syncthreads' vmcnt(0) drain: my data-atomics are LLC-complete
// before my flag add issues; consumers read data with bypassing atomics.
__device__ __forceinline__ void gbarR(int* c) {
  __syncthreads();
  if (threadIdx.x == 0) {
    __hip_atomic_fetch_add(c, 1, __ATOMIC_RELAXED, __HIP_MEMORY_SCOPE_AGENT);
    while (__hip_atomic_load(c, __ATOMIC_RELAXED, __HIP_MEMORY_SCOPE_AGENT) < 16)
      __builtin_amdgcn_s_sleep(1);
  }
  __syncthreads();
}

// ---- transpose+convert W_ih (f32 [k][n]) -> WT bf16 [n][k] (for gemm_p)
__global__ void wcvt_kernel(const float* __restrict__ W, short* __restrict__ WT) {
  __shared__ float tile[64][65];
  const int k0 = blockIdx.y * 64, n0 = blockIdx.x * 64;
  const int t = threadIdx.x;
#pragma unroll
  for (int i = 0; i < 16; i++) {
    int e = i * 256 + t, r = e >> 6, c = e & 63;
    tile[r][c] = W[(k0 + r) * Kd + n0 + c];
  }
  __syncthreads();
#pragma unroll
  for (int i = 0; i < 16; i++) {
    int e = i * 256 + t, rn = e >> 6, ck = e & 63;
    WT[(n0 + rn) * Kd + k0 + ck] = f2bf(tile[ck][rn]);
  }
}

// ---- convert W_hh into MFMA-B fragment layout
__global__ void wfrag_kernel(const float* __restrict__ W, short* __restrict__ Wf) {
  const int bid = blockIdx.x;  // nt*32 + kt
  const int nn = threadIdx.x & 15, kk = threadIdx.x >> 4;
  const int l = (kk >> 2) * 16 + nn;
  const int jj = (kk & 3) * 2;
  const int nt = bid >> 5, kt = bid & 31;
  const int n = nt * 16 + nn;
  const int k = kt * 32 + (kk >> 2) * 8 + jj;
  unsigned lo = (unsigned)(unsigned short)f2bf(W[(size_t)k * Kd + n]);
  unsigned hi = (unsigned)(unsigned short)f2bf(W[(size_t)(k + 1) * Kd + n]);
  ((unsigned*)Wf)[((size_t)bid * 64 + l) * 4 + (jj >> 1)] = lo | (hi << 16);
}

// ---- convert inp f32 -> bf16
__global__ void icvt_kernel(const float* __restrict__ inp, short* __restrict__ out) {
  int i = blockIdx.x * 2048 + threadIdx.x * 8;
  float4 a = *(const float4*)(inp + i);
  float4 b = *(const float4*)(inp + i + 4);
  s16x8 v;
  v[0] = f2bf(a.x); v[1] = f2bf(a.y); v[2] = f2bf(a.z); v[3] = f2bf(a.w);
  v[4] = f2bf(b.x); v[5] = f2bf(b.y); v[6] = f2bf(b.z); v[7] = f2bf(b.w);
  *(s16x8*)(out + i) = v;
}

// ---- P_raw = inp_bf16 @ W_ih
__global__ void __launch_bounds__(256) gemm_p_kernel(const short* __restrict__ A,
                                                     const short* __restrict__ BT,
                                                     short* __restrict__ C) {
  const int n0 = blockIdx.x * 64, m0 = blockIdx.y * 64;
  const int tid = threadIdx.x, w = tid >> 6, l = tid & 63, lm = l & 15, q = l >> 4;
  const short* ap = A + (m0 + w * 16 + lm) * Kd + q * 8;
  const short* bp = BT + (n0 + lm) * Kd + q * 8;
  f32x4 acc0 = {0.f, 0.f, 0.f, 0.f}, acc1 = acc0, acc2 = acc0, acc3 = acc0;
#pragma unroll 4
  for (int k = 0; k < Kd; k += 32) {
    s16x8 a = *(const s16x8*)(ap + k);
    s16x8 b0 = *(const s16x8*)(bp + k);
    s16x8 b1 = *(const s16x8*)(bp + 16 * Kd + k);
    s16x8 b2 = *(const s16x8*)(bp + 32 * Kd + k);
    s16x8 b3 = *(const s16x8*)(bp + 48 * Kd + k);
    acc0 = __builtin_amdgcn_mfma_f32_16x16x32_bf16(a, b0, acc0, 0, 0, 0);
    acc1 = __builtin_amdgcn_mfma_f32_16x16x32_bf16(a, b1, acc1, 0, 0, 0);
    acc2 = __builtin_amdgcn_mfma_f32_16x16x32_bf16(a, b2, acc2, 0, 0, 0);
    acc3 = __builtin_amdgcn_mfma_f32_16x16x32_bf16(a, b3, acc3, 0, 0, 0);
  }
  const int row = m0 + w * 16 + q * 4, col = n0 + lm;
#pragma unroll
  for (int r = 0; r < 4; r++) {
    C[(row + r) * Kd + col] = f2bf(acc0[r]);
    C[(row + r) * Kd + col + 16] = f2bf(acc1[r]);
    C[(row + r) * Kd + col + 32] = f2bf(acc2[r]);
    C[(row + r) * Kd + col + 48] = f2bf(acc3[r]);
  }
}

// ---- per-row mobius_matvec scaling of P; store pn2 = ||p||^2, pb2 = p.b
__global__ void __launch_bounds__(256) rowscale_kernel(const float* __restrict__ inp,
                                                       const float* __restrict__ bh,
                                                       short* __restrict__ P,
                                                       float* __restrict__ pn2,
                                                       float* __restrict__ pb2) {
  const int r = blockIdx.x, tid = threadIdx.x, i0 = tid * 4;
  float4 xv = *(const float4*)(inp + r * Kd + i0);
  float xn2 = brsum(xv.x * xv.x + xv.y * xv.y + xv.z * xv.z + xv.w * xv.w);
  s16x4 pr = *(const s16x4*)(P + r * Kd + i0);
  float p0 = bf2f(pr[0]), p1 = bf2f(pr[1]), p2 = bf2f(pr[2]), p3 = bf2f(pr[3]);
  float mxn2 = brsum(p0 * p0 + p1 * p1 + p2 * p2 + p3 * p3);
  float xn = fmaxf(sqrtf(xn2), EPSF);
  float mxn = fmaxf(sqrtf(mxn2), EPSF);
  float sc = tanhf(mxn / xn * atanhf(fminf(xn, ONEM))) / mxn;
  s16x4 po;
  po[0] = f2bf(sc * p0); po[1] = f2bf(sc * p1);
  po[2] = f2bf(sc * p2); po[3] = f2bf(sc * p3);
  *(s16x4*)(P + r * Kd + i0) = po;
  float4 bv = *(const float4*)(bh + i0);
  float s0 = bf2f(po[0]), s1 = bf2f(po[1]), s2v = bf2f(po[2]), s3 = bf2f(po[3]);
  float pn2v = brsum(s0 * s0 + s1 * s1 + s2v * s2v + s3 * s3);
  float pbv = brsum(s0 * bv.x + s1 * bv.y + s2v * bv.z + s3 * bv.w);
  if (tid == 0) { pn2[r] = pn2v; pb2[r] = pbv; }
}

// ---- phase 2: 256 blocks = 16 groups x 16 N-blocks; W_hh slice in registers;
// u exchanged via LLC (relaxed atomics), staged cooperatively into LDS once
// per block per step (R5 structure, rebuild replaced by LDS stage).
__global__ void __launch_bounds__(256, 1) rnn_kernel(
    const short* __restrict__ Wf, const short* __restrict__ P,
    const float* __restrict__ pn2, const float* __restrict__ pb2,
    const float* __restrict__ bh, float* __restrict__ out,
    float* __restrict__ S, int* __restrict__ cnt, ull* __restrict__ ubuf) {
  __shared__ short us[16][1032];  // staged u rows (stride 2064B: 2-way = free)
  __shared__ float red[4][16][4];
  __shared__ float bex[4];
  const int tid = threadIdx.x, w = tid >> 6, l = tid & 63, lm = l & 15, q = l >> 4;
  const int g = blockIdx.x & 15, nb = blockIdx.x >> 4;
  const int gr0 = g * 16;
  const int c = nb * 64 + w * 16 + lm;  // my output column
  const int nt = nb * 4 + w;            // Wf 16-col tile index

  // zero us (h0 = 0 for the t=0 GEMM)
  for (int i = tid; i < 8256; i += 256) ((int*)us)[i] = 0;

  // ---- b2 = ||b||^2 (block-wide) and my bias value
  float4 bv4 = *(const float4*)(bh + tid * 4);
  float bp = bv4.x * bv4.x + bv4.y * bv4.y + bv4.z * bv4.z + bv4.w * bv4.w;
#pragma unroll
  for (int m = 32; m >= 1; m >>= 1) bp += __shfl_xor(bp, m, 64);
  if (l == 0) bex[w] = bp;
  __syncthreads();  // covers us zero + bex
  const float b2 = bex[0] + bex[1] + bex[2] + bex[3];
  const float bb = bh[c];

  // ---- W_hh B-fragments for my 16-col strip: 32 x 16B = 128 VGPRs
  s16x8 wfr[32];
#pragma unroll
  for (int kt = 0; kt < 32; kt++)
    wfr[kt] = *(const s16x8*)(Wf + ((size_t)(nt * 32 + kt) * 64 + l) * 8);

  const short* ar = &us[0][0] + lm * 1032 + q * 8;  // A-frag base in LDS
  float lam[4] = {1.f, 1.f, 1.f, 1.f};
  float hn2c[4] = {0.f, 0.f, 0.f, 0.f};

  for (int t = 0; t < Tt; t++) {
    // prefetch p and per-row precomputed dots (plain loads: read-only inputs)
    float pv[4], p2s[4], pbr[4];
#pragma unroll
    for (int r = 0; r < 4; r++) {
      size_t rt = (size_t)(gr0 + q * 4 + r) * Tt + t;
      pv[r] = bf2f(P[rt * Kd + c]);
      p2s[r] = pn2[rt];
      pbr[r] = pb2[rt];
    }

    // ---- GEMM: u(t-1) @ W_hh (A-frags from LDS, B-frags registers)
    f32x4 c0 = {0.f, 0.f, 0.f, 0.f}, c1v = c0, c2v = c0, c3v = c0;
#pragma unroll
    for (int kt = 0; kt < 32; kt += 4) {
      s16x8 a0 = *(const s16x8*)(ar + (kt + 0) * 32);
      s16x8 a1 = *(const s16x8*)(ar + (kt + 1) * 32);
      s16x8 a2 = *(const s16x8*)(ar + (kt + 2) * 32);
      s16x8 a3 = *(const s16x8*)(ar + (kt + 3) * 32);
      c0 = __builtin_amdgcn_mfma_f32_16x16x32_bf16(a0, wfr[kt], c0, 0, 0, 0);
      c1v = __builtin_amdgcn_mfma_f32_16x16x32_bf16(a1, wfr[kt + 1], c1v, 0, 0, 0);
      c2v = __builtin_amdgcn_mfma_f32_16x16x32_bf16(a2, wfr[kt + 2], c2v, 0, 0, 0);
      c3v = __builtin_amdgcn_mfma_f32_16x16x32_bf16(a3, wfr[kt + 3], c3v, 0, 0, 0);
    }
    f32x4 accv = (c0 + c1v) + (c2v + c3v);
    float mx[4];
#pragma unroll
    for (int r = 0; r < 4; r++) mx[r] = lam[r] * accv[r];

    // ---- R1 partials: {mx^2, mx*b, p*mx} over my 16 cols
#pragma unroll
    for (int r = 0; r < 4; r++) {
      float vm2 = red16(mx[r] * mx[r]);
      float vmb = red16(mx[r] * bb);
      float vpm = red16(pv[r] * mx[r]);
      if (lm == 0) {
        red[w][q * 4 + r][0] = vm2;
        red[w][q * 4 + r][1] = vmb;
        red[w][q * 4 + r][2] = vpm;
      }
    }
    __syncthreads();
    float* Sg = S + ((size_t)t * 16 + g) * 64;  // [16 rows][4]
    if (tid < 64) {
      int row = tid >> 2, s = tid & 3;
      if (s < 3) {
        float v = red[0][row][s] + red[1][row][s] + red[2][row][s] + red[3][row][s];
        __hip_atomic_fetch_add(&Sg[row * 4 + s], v, __ATOMIC_RELAXED,
                               __HIP_MEMORY_SCOPE_AGENT);
      }
    }
    int* cg = cnt + ((size_t)t * 16 + g) * 16;  // 64B line per (t,g)
    gbarR(cg);

    // ---- read dots (ATOMIC: bypass stale L1/L2), scalar mobius algebra
    float uu[4], u2p[4];
#pragma unroll
    for (int r = 0; r < 4; r++) {
      PF d01;
      d01.u = __hip_atomic_load((ull*)Sg + (q * 4 + r) * 2, __ATOMIC_RELAXED,
                                __HIP_MEMORY_SCOPE_AGENT);
      float Spm = __hip_atomic_load(&Sg[(q * 4 + r) * 4 + 2], __ATOMIC_RELAXED,
                                    __HIP_MEMORY_SCOPE_AGENT);
      float Smm = d01.f[0], Smb = d01.f[1];
      float hn = fmaxf(sqrtf(hn2c[r]), EPSF);
      float mxn = fmaxf(sqrtf(Smm), EPSF);
      float sc = ftanh(mxn / hn * fatanh(fminf(hn, ONEM))) / mxn;
      float x2 = sc * sc * Smm;
      float xy = sc * Smb;
      float den = fmaxf(1.f + 2.f * xy + x2 * b2, EPSF);
      float al = ((1.f + 2.f * xy + b2) / den) * sc;  // hv = al*mx + be*b
      float be = (1.f - x2) / den;
      float hh2 = al * al * Smm + 2.f * al * be * Smb + be * be * b2;
      float ph = al * Spm + be * pbr[r];
      float den2 = fmaxf(1.f + 2.f * ph + p2s[r] * hh2, EPSF);
      float cc1 = (1.f + 2.f * ph + hh2) / den2;
      float cc2 = (1.f - p2s[r]) / den2;
      float z = cc1 * pv[r] + cc2 * (al * mx[r] + be * bb);
      float z2 = cc1 * cc1 * p2s[r] + cc2 * cc2 * hh2 + 2.f * cc1 * cc2 * ph;
      float zn = fmaxf(sqrtf(z2), EPSF);
      float gg = fatanh(fminf(zn, ONEM)) / zn;
      uu[r] = ftanh(gg * z);
      u2p[r] = red16(uu[r] * uu[r]);
    }

    // ---- R2: u exchange (packed 4xbf16 per 8B relaxed atomic) + u^2 sums
    const int p = t & 1;
    ull* ubw = ubuf + ((size_t)(p * 16 + g) * 16) * 256;  // [16 rows][256]
    const int ent = nb * 16 + w * 4 + (lm >> 2);
#pragma unroll
    for (int r = 0; r < 4; r++) {
      unsigned v16 = (unsigned)(unsigned short)f2bf(uu[r]);
      unsigned o1 = (unsigned)__shfl_xor((int)v16, 1, 64);
      unsigned plo = v16 | (o1 << 16);                       // even lm
      unsigned phi = (unsigned)__shfl_xor((int)plo, 2, 64);  // from lm+2
      if ((lm & 3) == 0) {
        ull pk = (ull)plo | ((ull)phi << 32);
        __hip_atomic_store(&ubw[(q * 4 + r) * 256 + ent], pk, __ATOMIC_RELAXED,
                           __HIP_MEMORY_SCOPE_AGENT);
      }
      if (lm == 0) red[w][q * 4 + r][3] = u2p[r];
    }
    __syncthreads();
    if (tid < 16) {
      float v = red[0][tid][3] + red[1][tid][3] + red[2][tid][3] + red[3][tid][3];
      __hip_atomic_fetch_add(&Sg[tid * 4 + 3], v, __ATOMIC_RELAXED,
                             __HIP_MEMORY_SCOPE_AGENT);
    }
    gbarR(cg + 8);

#pragma unroll
    for (int r = 0; r < 4; r++) {
      float u2 = __hip_atomic_load(&Sg[(q * 4 + r) * 4 + 3], __ATOMIC_RELAXED,
                                   __HIP_MEMORY_SCOPE_AGENT);
      float un = fmaxf(sqrtf(u2), EPSF);
      float s2 = ftanh(un) / un;
      lam[r] = s2;
      hn2c[r] = s2 * s2 * u2;
      if (t == Tt - 1)
        out[(size_t)(gr0 + q * 4 + r) * Kd + c] = s2 * uu[r];
    }

    // ---- cooperative stage of u(t) from LLC into LDS for next step's GEMM
    const ull* ub = ubuf + ((size_t)(p * 16 + g) * 16) * 256;
#pragma unroll
    for (int i = 0; i < 16; i++) {
      ull v = __hip_atomic_load(&ub[i * 256 + tid], __ATOMIC_RELAXED,
                                __HIP_MEMORY_SCOPE_AGENT);
      *(ull*)&us[i][tid * 4] = v;
    }
    __syncthreads();  // us ready before next GEMM
  }
}

extern "C" void kernel_launch(void* const* d_in, const int* in_sizes, int n_in,
                              void* d_out, int out_size, void* d_ws, size_t ws_size,
                              hipStream_t stream) {
  const float* inp = (const float*)d_in[0];  // [256][128][1024]
  const float* Wih = (const float*)d_in[1];  // [1024][1024]
  const float* Whh = (const float*)d_in[2];  // [1024][1024]
  const float* bh = (const float*)d_in[3];   // [1024]

  char* ws = (char*)d_ws;
  size_t off = 0;
  float* S = (float*)(ws + off); off += (size_t)Tt * 16 * 64 * 4;        // 512KB
  int* cnt = (int*)(ws + off); off += (size_t)Tt * 16 * 16 * 4;          // 128KB
  size_t zbytes = off;
  ull* ubuf = (ull*)(ws + off); off += (size_t)2 * 16 * 16 * 256 * 8;    // 1MB
  float* pn2 = (float*)(ws + off); off += (size_t)Bb * Tt * 4;           // 128KB
  float* pb2 = (float*)(ws + off); off += (size_t)Bb * Tt * 4;           // 128KB
  short* WTih = (short*)(ws + off); off += (size_t)Kd * Kd * 2;          // 2MB
  short* Wfhh = (short*)(ws + off); off += (size_t)Kd * Kd * 2;          // 2MB
  short* Ab = (short*)(ws + off); off += (size_t)Bb * Tt * Kd * 2;       // 64MB
  short* P = (short*)(ws + off); off += (size_t)Bb * Tt * Kd * 2;        // 64MB

  hipMemsetAsync(d_ws, 0, zbytes, stream);  // S sums + counters

  wcvt_kernel<<<dim3(16, 16), 256, 0, stream>>>(Wih, WTih);
  wfrag_kernel<<<2048, 256, 0, stream>>>(Whh, Wfhh);
  icvt_kernel<<<(Bb * Tt * Kd) / 2048, 256, 0, stream>>>(inp, Ab);
  gemm_p_kernel<<<dim3(16, (Bb * Tt) / 64), 256, 0, stream>>>(Ab, WTih, P);
  rowscale_kernel<<<Bb * Tt, 256, 0, stream>>>(inp, bh, P, pn2, pb2);
  rnn_kernel<<<256, 256, 0, stream>>>(Wfhh, P, pn2, pb2, bh, (float*)d_out,
                                      S, cnt, ubuf);
}